// Round 12
// baseline (291.714 us; speedup 1.0000x reference)
//
#include <hip/hip_runtime.h>
#include <hip/hip_bf16.h>
#include <math.h>

#define DIMC 1024
#define NHEADS 16
#define HDIM 64
#define BATCH 4
#define SEQ 2048
#define NROWS (BATCH * SEQ)      // 8192
#define ATTN_SCALE 0.125f        // 64^-0.5
#define LOG2E 1.4426950408889634f

typedef __attribute__((ext_vector_type(8))) short short8;   // 8 bf16 = 4 VGPR
typedef __attribute__((ext_vector_type(4))) short short4v;  // 4 bf16 = 2 VGPR
typedef __attribute__((ext_vector_type(4))) float f32x4;    // MFMA C/D

static __device__ __forceinline__ short f2bf(float f) {
    __hip_bfloat16 h = __float2bfloat16(f);
    return *reinterpret_cast<short*>(&h);
}

// async global->LDS, 16B per lane; LDS dest = wave-uniform base + lane*16
static __device__ __forceinline__ void gload16(const void* g, void* l) {
    __builtin_amdgcn_global_load_lds(
        (const __attribute__((address_space(1))) unsigned int*)g,
        (__attribute__((address_space(3))) unsigned int*)l, 16, 0, 0);
}

// ---------------------------------------------------------------------------
// prep: fused  (a) X fp32->bf16 copy  (b) w_qkv transpose+cvt  (c) w_proj t+cvt
// blocks [0,4096): xcvt; [4096,4864): w_qkv; [4864,5120): w_proj
// ---------------------------------------------------------------------------
__global__ __launch_bounds__(256)
void prep(const float* __restrict__ x, unsigned short* __restrict__ xbf,
          const float* __restrict__ wq, unsigned short* __restrict__ wqt,
          const float* __restrict__ wp, unsigned short* __restrict__ wpt) {
    const int tid = threadIdx.x;
    int blk = blockIdx.x;
    if (blk < 4096) {                      // xcvt
        int i = blk * 256 + tid;
        const float4* p = reinterpret_cast<const float4*>(x) + 2 * i;
        float4 a = p[0], b = p[1];
        short8 pk;
        pk[0] = f2bf(a.x); pk[1] = f2bf(a.y); pk[2] = f2bf(a.z); pk[3] = f2bf(a.w);
        pk[4] = f2bf(b.x); pk[5] = f2bf(b.y); pk[6] = f2bf(b.z); pk[7] = f2bf(b.w);
        reinterpret_cast<short8*>(xbf)[i] = pk;
        return;
    }
    blk -= 4096;
    const float* src; unsigned short* dst; int N, cb, rb;
    if (blk < 768) { src = wq; dst = wqt; N = 3072; cb = (blk % 48) * 64; rb = (blk / 48) * 64; }
    else { blk -= 768; src = wp; dst = wpt; N = 1024; cb = (blk % 16) * 64; rb = (blk / 16) * 64; }

    __shared__ float t[64][65];
#pragma unroll
    for (int e = 0; e < 4; e++) {
        int idx = tid + e * 256;
        int row = idx >> 4;
        int c4 = (idx & 15) << 2;
        *reinterpret_cast<float4*>(&t[row][c4]) =
            *reinterpret_cast<const float4*>(&src[(size_t)(rb + row) * N + cb + c4]);
    }
    __syncthreads();
#pragma unroll
    for (int e = 0; e < 2; e++) {
        int idx = tid + e * 256;
        int col = idx >> 3;
        int k8 = (idx & 7) << 3;
        short8 pk;
#pragma unroll
        for (int j = 0; j < 8; j++) pk[j] = f2bf(t[k8 + j][col]);
        *reinterpret_cast<short8*>(&dst[(size_t)(cb + col) * 1024 + rb + k8]) = pk;
    }
}

// ---------------------------------------------------------------------------
// 4-phase counted-vmcnt GEMM K-loop (shared by qkv and proj):
//  - double-buffered LDS [2][128][64], proven XOR swizzle
//  - tile t+1's 4 staging pieces issued INSIDE tile t (piece0 at top ->
//    vmcnt(2) -> raw s_barrier -> 4 MFMA clusters with pieces1-3 interleaved
//    -> end barrier).  Loads never drain to 0 in steady state (T4/m218).
// ---------------------------------------------------------------------------
#define GEMM_STAGE(SRC_A, SRC_B, LDB, e, k0n, bu)                               \
    {                                                                           \
        int j_ = wave * 4 + (e);                                                \
        gload16(&SRC_A[(size_t)(rowbase + j_ * 8 + sr) * DIMC + (k0n) + sc],    \
                &Alds[bu][0][0] + j_ * 512);                                    \
        gload16(&SRC_B[(size_t)(colbase + j_ * 8 + sr) * (LDB) + (k0n) + sc],   \
                &Blds[bu][0][0] + j_ * 512);                                    \
    }

__global__ __launch_bounds__(256)
void qkv_gemm_mfma(const unsigned short* __restrict__ Xbf,
                   const unsigned short* __restrict__ Wt,
                   unsigned short* __restrict__ qo, unsigned short* __restrict__ ko,
                   unsigned short* __restrict__ vt) {
    __shared__ short Alds[2][128][64];   // 32 KB
    __shared__ short Blds[2][128][64];   // 32 KB
    const int tid = threadIdx.x;
    const int lane = tid & 63;
    const int wave = tid >> 6;
    const int wr = wave >> 1, wc = wave & 1;
    const int rowbase = blockIdx.y * 128;
    const int colbase = blockIdx.x * 128;
    const int g = lane >> 4, li = lane & 15;
    const int sr = lane >> 3;
    const int sc = ((lane & 7) ^ sr) * 8;       // pre-swizzled global chunk
    const int swk = li & 7;                     // read-side swizzle key

    f32x4 acc[4][4];
#pragma unroll
    for (int m = 0; m < 4; m++)
#pragma unroll
        for (int n = 0; n < 4; n++) acc[m][n] = (f32x4){0.f, 0.f, 0.f, 0.f};

    // prologue: stage tile 0 -> buf 0
#pragma unroll
    for (int e = 0; e < 4; e++) GEMM_STAGE(Xbf, Wt, 1024, e, 0, 0);

    for (int t = 0; t < 16; t++) {
        const int buf = t & 1;
        const int nbuf = buf ^ 1;
        const int nk0 = (t + 1) * 64;
        const bool more = (t < 15);
        if (more) {
            GEMM_STAGE(Xbf, Wt, 1024, 0, nk0, nbuf);
            asm volatile("s_waitcnt vmcnt(2)" ::: "memory");
        } else {
            asm volatile("s_waitcnt vmcnt(0)" ::: "memory");
        }
        asm volatile("s_barrier" ::: "memory");   // A: tile-t LDS ready

        short8 af[4], bfr[2];
        // phase 0: ks=0, n=0..1
#pragma unroll
        for (int m = 0; m < 4; m++)
            af[m] = *reinterpret_cast<const short8*>(
                &Alds[buf][wr * 64 + m * 16 + li][((0 + g) ^ swk) * 8]);
#pragma unroll
        for (int n = 0; n < 2; n++)
            bfr[n] = *reinterpret_cast<const short8*>(
                &Blds[buf][wc * 64 + n * 16 + li][((0 + g) ^ swk) * 8]);
        __builtin_amdgcn_s_setprio(1);
#pragma unroll
        for (int m = 0; m < 4; m++)
#pragma unroll
            for (int n = 0; n < 2; n++)
                acc[m][n] = __builtin_amdgcn_mfma_f32_16x16x32_bf16(
                    af[m], bfr[n], acc[m][n], 0, 0, 0);
        __builtin_amdgcn_s_setprio(0);
        if (more) GEMM_STAGE(Xbf, Wt, 1024, 1, nk0, nbuf);
        // phase 1: ks=0, n=2..3
#pragma unroll
        for (int n = 0; n < 2; n++)
            bfr[n] = *reinterpret_cast<const short8*>(
                &Blds[buf][wc * 64 + (n + 2) * 16 + li][((0 + g) ^ swk) * 8]);
        __builtin_amdgcn_s_setprio(1);
#pragma unroll
        for (int m = 0; m < 4; m++)
#pragma unroll
            for (int n = 0; n < 2; n++)
                acc[m][n + 2] = __builtin_amdgcn_mfma_f32_16x16x32_bf16(
                    af[m], bfr[n], acc[m][n + 2], 0, 0, 0);
        __builtin_amdgcn_s_setprio(0);
        if (more) GEMM_STAGE(Xbf, Wt, 1024, 2, nk0, nbuf);
        // phase 2: ks=1, n=0..1
#pragma unroll
        for (int m = 0; m < 4; m++)
            af[m] = *reinterpret_cast<const short8*>(
                &Alds[buf][wr * 64 + m * 16 + li][((4 + g) ^ swk) * 8]);
#pragma unroll
        for (int n = 0; n < 2; n++)
            bfr[n] = *reinterpret_cast<const short8*>(
                &Blds[buf][wc * 64 + n * 16 + li][((4 + g) ^ swk) * 8]);
        __builtin_amdgcn_s_setprio(1);
#pragma unroll
        for (int m = 0; m < 4; m++)
#pragma unroll
            for (int n = 0; n < 2; n++)
                acc[m][n] = __builtin_amdgcn_mfma_f32_16x16x32_bf16(
                    af[m], bfr[n], acc[m][n], 0, 0, 0);
        __builtin_amdgcn_s_setprio(0);
        if (more) GEMM_STAGE(Xbf, Wt, 1024, 3, nk0, nbuf);
        // phase 3: ks=1, n=2..3
#pragma unroll
        for (int n = 0; n < 2; n++)
            bfr[n] = *reinterpret_cast<const short8*>(
                &Blds[buf][wc * 64 + (n + 2) * 16 + li][((4 + g) ^ swk) * 8]);
        __builtin_amdgcn_s_setprio(1);
#pragma unroll
        for (int m = 0; m < 4; m++)
#pragma unroll
            for (int n = 0; n < 2; n++)
                acc[m][n + 2] = __builtin_amdgcn_mfma_f32_16x16x32_bf16(
                    af[m], bfr[n], acc[m][n + 2], 0, 0, 0);
        __builtin_amdgcn_s_setprio(0);
        asm volatile("s_barrier" ::: "memory");   // B: all reads of buf done
    }

    const int col0 = colbase + wc * 64;
    const int three = col0 >> 10;
    const int h = (col0 & 1023) >> 6;
    if (three < 2) {
        unsigned short* dst = (three == 0) ? qo : ko;
        const float mult = (three == 0) ? (ATTN_SCALE * LOG2E) : 1.0f;
#pragma unroll
        for (int n = 0; n < 4; n++) {
            int d = n * 16 + li;
#pragma unroll
            for (int m = 0; m < 4; m++) {
                int r0 = rowbase + wr * 64 + m * 16 + g * 4;
                int b = r0 >> 11;
                size_t base = ((size_t)(b * NHEADS + h) * SEQ) * HDIM + d;
#pragma unroll
                for (int r = 0; r < 4; r++) {
                    int s = (r0 + r) & 2047;
                    dst[base + (size_t)s * HDIM] = (unsigned short)f2bf(acc[m][n][r] * mult);
                }
            }
        }
    } else {
#pragma unroll
        for (int n = 0; n < 4; n++) {
            int d = n * 16 + li;
#pragma unroll
            for (int m = 0; m < 4; m++) {
                int r0 = rowbase + wr * 64 + m * 16 + g * 4;
                int b = r0 >> 11, s0 = r0 & 2047;
                short4v pk;
#pragma unroll
                for (int r = 0; r < 4; r++) pk[r] = f2bf(acc[m][n][r]);
                *reinterpret_cast<short4v*>(
                    &vt[((size_t)(b * NHEADS + h) * HDIM + d) * SEQ + s0]) = pk;
            }
        }
    }
}

__global__ __launch_bounds__(256)
void proj_gemm_mfma(const unsigned short* __restrict__ Abf,
                    const unsigned short* __restrict__ Wt,
                    const float* __restrict__ bias, float* __restrict__ out) {
    __shared__ short Alds[2][128][64];
    __shared__ short Blds[2][128][64];
    const int tid = threadIdx.x;
    const int lane = tid & 63;
    const int wave = tid >> 6;
    const int wr = wave >> 1, wc = wave & 1;
    const int rowbase = blockIdx.y * 128;
    const int colbase = blockIdx.x * 128;
    const int g = lane >> 4, li = lane & 15;
    const int sr = lane >> 3;
    const int sc = ((lane & 7) ^ sr) * 8;
    const int swk = li & 7;

    f32x4 acc[4][4];
#pragma unroll
    for (int m = 0; m < 4; m++)
#pragma unroll
        for (int n = 0; n < 4; n++) acc[m][n] = (f32x4){0.f, 0.f, 0.f, 0.f};

#pragma unroll
    for (int e = 0; e < 4; e++) GEMM_STAGE(Abf, Wt, 1024, e, 0, 0);

    for (int t = 0; t < 16; t++) {
        const int buf = t & 1;
        const int nbuf = buf ^ 1;
        const int nk0 = (t + 1) * 64;
        const bool more = (t < 15);
        if (more) {
            GEMM_STAGE(Abf, Wt, 1024, 0, nk0, nbuf);
            asm volatile("s_waitcnt vmcnt(2)" ::: "memory");
        } else {
            asm volatile("s_waitcnt vmcnt(0)" ::: "memory");
        }
        asm volatile("s_barrier" ::: "memory");

        short8 af[4], bfr[2];
#pragma unroll
        for (int m = 0; m < 4; m++)
            af[m] = *reinterpret_cast<const short8*>(
                &Alds[buf][wr * 64 + m * 16 + li][((0 + g) ^ swk) * 8]);
#pragma unroll
        for (int n = 0; n < 2; n++)
            bfr[n] = *reinterpret_cast<const short8*>(
                &Blds[buf][wc * 64 + n * 16 + li][((0 + g) ^ swk) * 8]);
        __builtin_amdgcn_s_setprio(1);
#pragma unroll
        for (int m = 0; m < 4; m++)
#pragma unroll
            for (int n = 0; n < 2; n++)
                acc[m][n] = __builtin_amdgcn_mfma_f32_16x16x32_bf16(
                    af[m], bfr[n], acc[m][n], 0, 0, 0);
        __builtin_amdgcn_s_setprio(0);
        if (more) GEMM_STAGE(Abf, Wt, 1024, 1, nk0, nbuf);
#pragma unroll
        for (int n = 0; n < 2; n++)
            bfr[n] = *reinterpret_cast<const short8*>(
                &Blds[buf][wc * 64 + (n + 2) * 16 + li][((0 + g) ^ swk) * 8]);
        __builtin_amdgcn_s_setprio(1);
#pragma unroll
        for (int m = 0; m < 4; m++)
#pragma unroll
            for (int n = 0; n < 2; n++)
                acc[m][n + 2] = __builtin_amdgcn_mfma_f32_16x16x32_bf16(
                    af[m], bfr[n], acc[m][n + 2], 0, 0, 0);
        __builtin_amdgcn_s_setprio(0);
        if (more) GEMM_STAGE(Abf, Wt, 1024, 2, nk0, nbuf);
#pragma unroll
        for (int m = 0; m < 4; m++)
            af[m] = *reinterpret_cast<const short8*>(
                &Alds[buf][wr * 64 + m * 16 + li][((4 + g) ^ swk) * 8]);
#pragma unroll
        for (int n = 0; n < 2; n++)
            bfr[n] = *reinterpret_cast<const short8*>(
                &Blds[buf][wc * 64 + n * 16 + li][((4 + g) ^ swk) * 8]);
        __builtin_amdgcn_s_setprio(1);
#pragma unroll
        for (int m = 0; m < 4; m++)
#pragma unroll
            for (int n = 0; n < 2; n++)
                acc[m][n] = __builtin_amdgcn_mfma_f32_16x16x32_bf16(
                    af[m], bfr[n], acc[m][n], 0, 0, 0);
        __builtin_amdgcn_s_setprio(0);
        if (more) GEMM_STAGE(Abf, Wt, 1024, 3, nk0, nbuf);
#pragma unroll
        for (int n = 0; n < 2; n++)
            bfr[n] = *reinterpret_cast<const short8*>(
                &Blds[buf][wc * 64 + (n + 2) * 16 + li][((4 + g) ^ swk) * 8]);
        __builtin_amdgcn_s_setprio(1);
#pragma unroll
        for (int m = 0; m < 4; m++)
#pragma unroll
            for (int n = 0; n < 2; n++)
                acc[m][n + 2] = __builtin_amdgcn_mfma_f32_16x16x32_bf16(
                    af[m], bfr[n], acc[m][n + 2], 0, 0, 0);
        __builtin_amdgcn_s_setprio(0);
        asm volatile("s_barrier" ::: "memory");
    }

#pragma unroll
    for (int n = 0; n < 4; n++) {
        int col = colbase + wc * 64 + n * 16 + li;
        float bv = bias[col];
#pragma unroll
        for (int m = 0; m < 4; m++) {
            int r0 = rowbase + wr * 64 + m * 16 + g * 4;
#pragma unroll
            for (int r = 0; r < 4; r++)
                out[(size_t)(r0 + r) * DIMC + col] = acc[m][n][r] + bv;
        }
    }
}

// ---------------------------------------------------------------------------
// MFMA flash attention — UNCHANGED from round 11 (verified).
// ---------------------------------------------------------------------------
__global__ __launch_bounds__(512)
void flash_attn_mfma(const unsigned short* __restrict__ qg,
                     const unsigned short* __restrict__ kg,
                     const unsigned short* __restrict__ vt,
                     unsigned short* __restrict__ og) {
    __shared__ short Klds[2][64][64];   // 16 KB
    __shared__ short Vlds[2][64][64];   // 16 KB
    const int tid = threadIdx.x;
    const int lane = tid & 63;
    const int w = tid >> 6;             // 0..7
    const int g = lane >> 4, li = lane & 15;
    const int orig = blockIdx.x;                   // 0..511
    const int swz = (orig & 7) * 64 + (orig >> 3);
    const int bx = swz & 7;                        // q-tile pair index
    const int bh = swz >> 3;                       // head 0..63
    const size_t head = (size_t)bh * SEQ * HDIM;
    const int b = bh >> 4, h = bh & 15;

    const int c0r = tid >> 3, c0c = tid & 7;       // one 16B chunk per thread

    const int abase0 = 8 * (li >> 2) + (li & 3);       // m even
    const int abase1 = abase0 + 4;                     // m odd

    for (int pass = 0; pass < 2; pass++) {
        const int qtile = pass ? (15 - bx) : bx;
        const int qbase = qtile * 128;
        const int qw = qbase + w * 16;             // 16 q-rows per wave
        const int nt = 2 * qtile + 2;

        short8 bq[2];
#pragma unroll
        for (int ds = 0; ds < 2; ds++)
            bq[ds] = *reinterpret_cast<const short8*>(
                &qg[head + (size_t)(qw + li) * HDIM + ds * 32 + g * 8]);

        f32x4 accO[4];
#pragma unroll
        for (int df = 0; df < 4; df++) accO[df] = (f32x4){0.f, 0.f, 0.f, 0.f};
        float mrow = -INFINITY;
        float lrow = 0.f;

        const unsigned short* kp = kg + head + (size_t)c0r * HDIM + c0c * 8;
        const unsigned short* vp = vt + head + (size_t)c0r * SEQ + c0c * 8;

        short8 kreg, vreg;
        kreg = *reinterpret_cast<const short8*>(kp);
        vreg = *reinterpret_cast<const short8*>(vp);
        kp += 64 * HDIM; vp += 64;
        {
            const int sw0 = (c0c ^ (c0r & 7)) * 8;
            *reinterpret_cast<short8*>(&Klds[0][c0r][sw0]) = kreg;
            *reinterpret_cast<short8*>(&Vlds[0][c0r][sw0]) = vreg;
        }
        __syncthreads();

        for (int t = 0; t < nt; t++) {
            const int kvbase = t * 64;
            const int buf = t & 1;
            const bool more = (t + 1 < nt);
            if (more) {
                kreg = *reinterpret_cast<const short8*>(kp);
                vreg = *reinterpret_cast<const short8*>(vp);
                kp += 64 * HDIM; vp += 64;
            }

            if (kvbase <= qw + 15) {
                f32x4 s[4];
#pragma unroll
                for (int m = 0; m < 4; m++) s[m] = (f32x4){0.f, 0.f, 0.f, 0.f};
#pragma unroll
                for (int ds = 0; ds < 2; ds++) {
                    short8 ak[4];
#pragma unroll
                    for (int m = 0; m < 4; m++) {
                        int arow = 32 * (m >> 1) + ((m & 1) ? abase1 : abase0);
                        ak[m] = *reinterpret_cast<const short8*>(
                            &Klds[buf][arow][((ds * 4 + g) ^ (arow & 7)) * 8]);
                    }
                    __builtin_amdgcn_s_setprio(1);
#pragma unroll
                    for (int m = 0; m < 4; m++)
                        s[m] = __builtin_amdgcn_mfma_f32_16x16x32_bf16(
                            ak[m], bq[ds], s[m], 0, 0, 0);
                    __builtin_amdgcn_s_setprio(0);
                }
                const bool diag = (kvbase + 63 > qw);
                if (diag) {
                    int q = qw + li;
#pragma unroll
                    for (int m = 0; m < 4; m++) {
                        int kv0 = kvbase + 32 * (m >> 1) + 8 * g + 4 * (m & 1);
#pragma unroll
                        for (int r = 0; r < 4; r++)
                            if (kv0 + r > q) s[m][r] = -INFINITY;
                    }
                }
                float a0 = fmaxf(fmaxf(s[0][0], s[0][1]), fmaxf(s[0][2], s[0][3]));
                float a1 = fmaxf(fmaxf(s[1][0], s[1][1]), fmaxf(s[1][2], s[1][3]));
                float a2 = fmaxf(fmaxf(s[2][0], s[2][1]), fmaxf(s[2][2], s[2][3]));
                float a3 = fmaxf(fmaxf(s[3][0], s[3][1]), fmaxf(s[3][2], s[3][3]));
                float tm = fmaxf(fmaxf(a0, a1), fmaxf(a2, a3));
                tm = fmaxf(tm, __shfl_xor(tm, 16));
                tm = fmaxf(tm, __shfl_xor(tm, 32));
                float mnew = fmaxf(mrow, tm);
                float corr = __builtin_amdgcn_exp2f(mrow - mnew);
                mrow = mnew;
                float p[4][4];
                float sm[4];
#pragma unroll
                for (int m = 0; m < 4; m++) {
#pragma unroll
                    for (int r = 0; r < 4; r++)
                        p[m][r] = __builtin_amdgcn_exp2f(s[m][r] - mrow);
                    sm[m] = (p[m][0] + p[m][1]) + (p[m][2] + p[m][3]);
                }
                short8 bp[2];
#pragma unroll
                for (int ks = 0; ks < 2; ks++) {
                    unsigned u0 = (__float_as_uint(p[2 * ks][1]) & 0xFFFF0000u) |
                                  (__float_as_uint(p[2 * ks][0]) >> 16);
                    unsigned u1 = (__float_as_uint(p[2 * ks][3]) & 0xFFFF0000u) |
                                  (__float_as_uint(p[2 * ks][2]) >> 16);
                    unsigned u2 = (__float_as_uint(p[2 * ks + 1][1]) & 0xFFFF0000u) |
                                  (__float_as_uint(p[2 * ks + 1][0]) >> 16);
                    unsigned u3 = (__float_as_uint(p[2 * ks + 1][3]) & 0xFFFF0000u) |
                                  (__float_as_uint(p[2 * ks + 1][2]) >> 16);
                    unsigned q4[4] = {u0, u1, u2, u3};
                    bp[ks] = *reinterpret_cast<short8*>(q4);
                }
                float ts = (sm[0] + sm[1]) + (sm[2] + sm[3]);
                ts += __shfl_xor(ts, 16);
                ts += __shfl_xor(ts, 32);
                lrow = lrow * corr + ts;
                if (!__all((int)(corr == 1.0f))) {
#pragma unroll
                    for (int df = 0; df < 4; df++) {
                        accO[df][0] *= corr; accO[df][1] *= corr;
                        accO[df][2] *= corr; accO[df][3] *= corr;
                    }
                }
#pragma unroll
                for (int ks = 0; ks < 2; ks++) {
                    short8 av[4];
#pragma unroll
                    for (int df = 0; df < 4; df++) {
                        int vrow = li + 16 * df;
                        av[df] = *reinterpret_cast<const short8*>(
                            &Vlds[buf][vrow][((ks * 4 + g) ^ (vrow & 7)) * 8]);
                    }
                    __builtin_amdgcn_s_setprio(1);
#pragma unroll
                    for (int df = 0; df < 4; df++)
                        accO[df] = __builtin_amdgcn_mfma_f32_16x16x32_bf16(
                            av[df], bp[ks], accO[df], 0, 0, 0);
                    __builtin_amdgcn_s_setprio(0);
                }
            }

            if (more) {
                const int nbuf = buf ^ 1;
                const int sw0 = (c0c ^ (c0r & 7)) * 8;
                *reinterpret_cast<short8*>(&Klds[nbuf][c0r][sw0]) = kreg;
                *reinterpret_cast<short8*>(&Vlds[nbuf][c0r][sw0]) = vreg;
            }
            __syncthreads();
        }

        {
            float inv = 1.0f / lrow;
            int q = qw + li;
            size_t rowoff = (size_t)(b * SEQ + q) * DIMC + h * HDIM;
#pragma unroll
            for (int df = 0; df < 4; df++) {
                short4v pk;
#pragma unroll
                for (int r = 0; r < 4; r++) pk[r] = f2bf(accO[df][r] * inv);
                *reinterpret_cast<short4v*>(&og[rowoff + 16 * df + 4 * g]) = pk;
            }
        }
        __syncthreads();
    }
}

extern "C" void kernel_launch(void* const* d_in, const int* in_sizes, int n_in,
                              void* d_out, int out_size, void* d_ws, size_t ws_size,
                              hipStream_t stream) {
    const float* x      = (const float*)d_in[0];   // [4,2048,1024]
    const float* w_qkv  = (const float*)d_in[1];   // [1024,3072]
    const float* w_proj = (const float*)d_in[2];   // [1024,1024]
    const float* b_proj = (const float*)d_in[3];   // [1024]
    float* out = (float*)d_out;                    // [4,2048,1024] fp32

    char* w = (char*)d_ws;
    unsigned short* qb  = (unsigned short*)(w);                        // 16 MB
    unsigned short* kb  = (unsigned short*)(w + ((size_t)16 << 20));   // 16 MB
    unsigned short* vtb = (unsigned short*)(w + ((size_t)32 << 20));   // 16 MB [B,H,D,S]
    unsigned short* ao  = (unsigned short*)(w + ((size_t)48 << 20));   // 16 MB
    unsigned short* wqt = (unsigned short*)(w + ((size_t)64 << 20));   // 6 MB
    unsigned short* wpt = (unsigned short*)(w + ((size_t)72 << 20));   // 2 MB
    unsigned short* xbf = (unsigned short*)(w + ((size_t)80 << 20));   // 16 MB

    prep<<<4096 + 768 + 256, 256, 0, stream>>>(x, xbf, w_qkv, wqt, w_proj, wpt);
    qkv_gemm_mfma<<<dim3(3 * DIMC / 128, NROWS / 128), 256, 0, stream>>>(xbf, wqt, qb, kb, vtb);
    flash_attn_mfma<<<512, 512, 0, stream>>>(qb, kb, vtb, ao);
    proj_gemm_mfma<<<dim3(DIMC / 128, NROWS / 128), 256, 0, stream>>>(ao, wpt, b_proj, out);
}